// Round 13
// baseline (3165.256 us; speedup 1.0000x reference)
//
#include <hip/hip_runtime.h>
#include <cstddef>

#define T_STEPS 1024
#define NB      64
#define DIN     128
#define HID     256

typedef unsigned short u16;
typedef unsigned int   u32;
typedef unsigned long long u64;
typedef __attribute__((ext_vector_type(8))) short short8;
typedef __attribute__((ext_vector_type(4))) float f32x4;

// ws byte offsets
#define WG_OFF   0u          // bf16 weights [2][1024 rows j*4+q][384 k] = 1,572,864 B
#define BIAS_OFF 1572864u    // f32 [2][1024]
#define XB_OFF   1581056u    // bf16 x [1024][64][128] = 16,777,216 B
#define HB_OFF   18358272u   // u16 hbuf [2 par][8 grp][16 b][256 j] = 131,072 B
#define FL_OFF   18489344u   // u32 flags [8 grp][16 wg] = 512 B

#define OUT_MAIN (T_STEPS * NB * 2 * HID)
#define TAIL_H   OUT_MAIN
#define TAIL_C   (OUT_MAIN + 2 * NB * HID)

__device__ __forceinline__ u16 f2bf(float f) {
  unsigned u = __float_as_uint(f);
  return (u16)((u + 0x7fffu + ((u >> 16) & 1u)) >> 16);  // RNE
}
__device__ __forceinline__ float sigm(float v) { return 1.f / (1.f + __expf(-v)); }
__device__ __forceinline__ float tanh_fast(float x) {
  float e = __expf(-2.f * fabsf(x));
  float r = (1.f - e) / (1.f + e);
  return x < 0.f ? -r : r;
}

__global__ void prep_kernel(const float* __restrict__ x,
                            const float* __restrict__ Wih_f, const float* __restrict__ Whh_f,
                            const float* __restrict__ bih_f, const float* __restrict__ bhh_f,
                            const float* __restrict__ Wih_r, const float* __restrict__ Whh_r,
                            const float* __restrict__ bih_r, const float* __restrict__ bhh_r,
                            const float* __restrict__ hx,
                            u16* __restrict__ Wg, float* __restrict__ bias4,
                            u16* __restrict__ xb, u16* __restrict__ hbuf,
                            u32* __restrict__ flags) {
  // segments: W 786432 | bias 2048 | xb 8388608 | hx-cells 32768 | flags 128
  const int total = 786432 + 2048 + 8388608 + 32768 + 128;
  for (int i = blockIdx.x * blockDim.x + threadIdx.x; i < total;
       i += gridDim.x * blockDim.x) {
    if (i < 786432) {
      int d = i / 393216;
      int r = i - d * 393216;
      int rowg = r / 384, k = r - rowg * 384;   // rowg = j*4+q interleaved
      int j = rowg >> 2, q = rowg & 3;
      int g = q * HID + j;                      // torch gate row
      const float* Wih = d ? Wih_r : Wih_f;
      const float* Whh = d ? Whh_r : Whh_f;
      float v = (k < DIN) ? Wih[g * DIN + k] : Whh[g * HID + (k - DIN)];
      Wg[i] = f2bf(v);
    } else if (i < 786432 + 2048) {
      int r = i - 786432;
      int d = r >> 10, rowg = r & 1023;
      int j = rowg >> 2, q = rowg & 3;
      int g = q * HID + j;
      bias4[r] = d ? (bih_r[g] + bhh_r[g]) : (bih_f[g] + bhh_f[g]);
    } else if (i < 786432 + 2048 + 8388608) {
      int r = i - (786432 + 2048);
      xb[r] = f2bf(x[r]);                       // [t][b][k]
    } else if (i < 786432 + 2048 + 8388608 + 32768) {
      int r = i - (786432 + 2048 + 8388608);    // (d*64+b)*256 + j
      int d = r >> 14, b = (r >> 8) & 63, j = r & 255;
      int grp = d * 4 + (b >> 4), bb = b & 15;
      hbuf[((size_t)(8 + grp) * 16 + bb) * 256 + j] = f2bf(hx[r]);  // parity 1
      hbuf[((size_t)(0 + grp) * 16 + bb) * 256 + j] = 0;            // parity 0
    } else {
      flags[i - (786432 + 2048 + 8388608 + 32768)] = 0u;
    }
  }
}

#define MFMA __builtin_amdgcn_mfma_f32_16x16x32_bf16
#define ALD64(P) __hip_atomic_load((P), __ATOMIC_RELAXED, __HIP_MEMORY_SCOPE_AGENT)
#define MN2(F) { u32 a_ = (u32)(F), b_ = (u32)((F) >> 32); \
                 mn = mn < a_ ? mn : a_; mn = mn < b_ ? mn : b_; }

// 128 WGs x 256 thr. grp = bid&7 = d*4+btile (16 WGs/group), jsl = bid>>3.
// Per WG: 64 gate rows, 16 batches. Step-invariant weight fragments in named
// VGPRs (no per-step weight LDS reads). Exchange: r9 parity protocol with
// per-producer value flags (plain stores, no RMW) + wave-autonomous polling.
// 2 barriers/step: B1 (h parked) and B2 (h stores drained).
__global__ __launch_bounds__(256, 1) void lstm_r13(
    const u16* __restrict__ Wg, const float* __restrict__ bias4,
    const u16* __restrict__ xb, const float* __restrict__ cx,
    u16* __restrict__ hbuf, u32* __restrict__ flags,
    float* __restrict__ out) {
  extern __shared__ char smem[];
  u16* xsh  = (u16*)smem;                 // [2][16][136]  8,704 B
  u16* hsh  = (u16*)(smem + 8704);        // [16][264]     8,448 B
  float* gl = (float*)(smem + 17152);     // [4 wave][16 m][20] 5,120 B (tot 22,272)

  const int tid = threadIdx.x;
  const int bid = blockIdx.x;
  const int grp = bid & 7;
  const int jsl = bid >> 3;
  const int d = grp >> 2, b0 = (grp & 3) * 16;
  const int w = tid >> 6, l = tid & 63;

  // one-time: weight fragments -> named VGPRs (global, 16-B aligned)
  const u16* wgb = Wg + ((size_t)(d * 1024 + jsl * 64 + w * 16 + (l & 15))) * 384
                      + (l >> 4) * 8;
  short8 Wx0 = *(const short8*)(wgb + 0);
  short8 Wx1 = *(const short8*)(wgb + 32);
  short8 Wx2 = *(const short8*)(wgb + 64);
  short8 Wx3 = *(const short8*)(wgb + 96);
  short8 Wh0 = *(const short8*)(wgb + 128);
  short8 Wh1 = *(const short8*)(wgb + 160);
  short8 Wh2 = *(const short8*)(wgb + 192);
  short8 Wh3 = *(const short8*)(wgb + 224);
  short8 Wh4 = *(const short8*)(wgb + 256);
  short8 Wh5 = *(const short8*)(wgb + 288);
  short8 Wh6 = *(const short8*)(wgb + 320);
  short8 Wh7 = *(const short8*)(wgb + 352);
  const float bv = bias4[d * 1024 + jsl * 64 + w * 16 + (l & 15)];

  // elementwise identity (wave-local): eb = batch, ejl = j-slot within wave
  const int eb = l >> 2, ejl = l & 3;
  const int jglob = jsl * 16 + w * 4 + ejl;
  float c_reg = cx[((size_t)d * NB + b0 + eb) * HID + jglob];
  float* glw = gl + w * 320;              // per-wave slab [16 m][20]

  const int xr_row = tid >> 4;            // x stage row (16 batches)
  const int xc = (tid & 15) * 8;          // 8 u16 = 16 B per thread
  const int pb = tid >> 4;                // h consumer batch
  const int cj0 = (tid & 15) * 16;        // 16 h cells per thread

  // prologue: stage x(t0), prefetch x(t1), issue h(init) loads (parity 1)
  { int t0 = d ? 1023 : 0;
    *(uint4*)&xsh[(0 * 16 + xr_row) * 136 + xc] =
        *(const uint4*)&xb[((size_t)t0 * NB + b0 + xr_row) * DIN + xc]; }
  uint4 xv;
  { int t1 = d ? 1022 : 1;
    xv = *(const uint4*)&xb[((size_t)t1 * NB + b0 + xr_row) * DIN + xc]; }
  u64 h0, h1, h2, h3;
  { const u64* hp = (const u64*)(hbuf + ((size_t)(8 + grp) * 16 + pb) * 256 + cj0);
    h0 = ALD64(hp + 0); h1 = ALD64(hp + 1); h2 = ALD64(hp + 2); h3 = ALD64(hp + 3); }
  __syncthreads();

  for (int s = 0; s < T_STEPS; ++s) {
    const int p = s & 1;
    const int t = d ? (1023 - s) : s;

    // park x(s+1) into the other buffer (xsh[p] was read last iter, safe post-B2)
    if (s < 1023) *(uint4*)&xsh[((p ^ 1) * 16 + xr_row) * 136 + xc] = xv;

    // x-part MFMA from registers+LDS (hides in-flight h loads)
    f32x4 acc = {bv, bv, bv, bv};
    {
      const u16* xr = &xsh[(p * 16 + (l & 15)) * 136 + (l >> 4) * 8];
      acc = MFMA(*(const short8*)(xr + 0),  Wx0, acc, 0, 0, 0);
      acc = MFMA(*(const short8*)(xr + 32), Wx1, acc, 0, 0, 0);
      acc = MFMA(*(const short8*)(xr + 64), Wx2, acc, 0, 0, 0);
      acc = MFMA(*(const short8*)(xr + 96), Wx3, acc, 0, 0, 0);
    }
    // park h (waits vmcnt on h regs only)
    {
      uint4 H0, H1;
      H0.x = (u32)h0; H0.y = (u32)(h0 >> 32); H0.z = (u32)h1; H0.w = (u32)(h1 >> 32);
      H1.x = (u32)h2; H1.y = (u32)(h2 >> 32); H1.z = (u32)h3; H1.w = (u32)(h3 >> 32);
      *(uint4*)&hsh[pb * 264 + cj0] = H0;
      *(uint4*)&hsh[pb * 264 + cj0 + 8] = H1;
    }
    asm volatile("s_waitcnt lgkmcnt(0)" ::: "memory");
    __builtin_amdgcn_s_barrier();                // B1: h parked

    // h-part MFMA: weights from registers, h fragments from LDS
    {
      const u16* hr = &hsh[(l & 15) * 264 + (l >> 4) * 8];
      acc = MFMA(*(const short8*)(hr + 0),   Wh0, acc, 0, 0, 0);
      acc = MFMA(*(const short8*)(hr + 32),  Wh1, acc, 0, 0, 0);
      acc = MFMA(*(const short8*)(hr + 64),  Wh2, acc, 0, 0, 0);
      acc = MFMA(*(const short8*)(hr + 96),  Wh3, acc, 0, 0, 0);
      acc = MFMA(*(const short8*)(hr + 128), Wh4, acc, 0, 0, 0);
      acc = MFMA(*(const short8*)(hr + 160), Wh5, acc, 0, 0, 0);
      acc = MFMA(*(const short8*)(hr + 192), Wh6, acc, 0, 0, 0);
      acc = MFMA(*(const short8*)(hr + 224), Wh7, acc, 0, 0, 0);
    }
    // gates -> per-wave slab [m][n], n = local gate row (wave-private, no barrier)
    {
      int n = l & 15;
      int m0 = (l >> 4) * 4;
      glw[(m0 + 0) * 20 + n] = acc[0]; glw[(m0 + 1) * 20 + n] = acc[1];
      glw[(m0 + 2) * 20 + n] = acc[2]; glw[(m0 + 3) * 20 + n] = acc[3];
    }
    asm volatile("s_waitcnt lgkmcnt(0)" ::: "memory");  // wave-local write->read

    // elementwise (wave-local 4 j-slots x 16 batches) + h publish + out
    float h, c;
    {
      f32x4 g4 = *(const f32x4*)&glw[eb * 20 + ejl * 4];
      float ii = sigm(g4[0]), ffg = sigm(g4[1]);
      float gg = tanh_fast(g4[2]), oo = sigm(g4[3]);
      c = ffg * c_reg + ii * gg;
      c_reg = c;
      h = oo * tanh_fast(c);
      __hip_atomic_store(hbuf + ((size_t)(p * 8 + grp) * 16 + eb) * 256 + jglob,
                         f2bf(h), __ATOMIC_RELAXED, __HIP_MEMORY_SCOPE_AGENT);
      out[((size_t)t * NB + b0 + eb) * (2 * HID) + d * HID + jglob] = h;
      if (s == 1023) {
        out[TAIL_H + ((size_t)d * NB + b0 + eb) * HID + jglob] = h;
        out[TAIL_C + ((size_t)d * NB + b0 + eb) * HID + jglob] = c;
      }
    }
    asm volatile("s_waitcnt vmcnt(0)" ::: "memory");   // h (and out) drained
    __builtin_amdgcn_s_barrier();                // B2: all stores at LLC

    if (s < 1023) {
      // publish per-producer flag (plain relaxed store, no RMW)
      if (tid == 0)
        __hip_atomic_store(flags + grp * 16 + jsl, (u32)(s + 1),
                           __ATOMIC_RELAXED, __HIP_MEMORY_SCOPE_AGENT);
      // x prefetch for s+2 (in flight across the poll)
      if (s < 1022) {
        int tn = d ? (1021 - s) : (s + 2);
        xv = *(const uint4*)&xb[((size_t)tn * NB + b0 + xr_row) * DIN + xc];
      }
      // wave-autonomous poll: all lanes load the uniform 16-flag line
      {
        const u64* fl = (const u64*)(flags + grp * 16);
        const u32 want = (u32)(s + 1);
        while (1) {
          u64 f0 = ALD64(fl + 0), f1 = ALD64(fl + 1), f2 = ALD64(fl + 2), f3 = ALD64(fl + 3);
          u64 f4 = ALD64(fl + 4), f5 = ALD64(fl + 5), f6 = ALD64(fl + 6), f7 = ALD64(fl + 7);
          u32 mn = 0xffffffffu;
          MN2(f0) MN2(f1) MN2(f2) MN2(f3) MN2(f4) MN2(f5) MN2(f6) MN2(f7)
          if (mn >= want) break;
        }
      }
      // issue h(s) loads (parity p) -- consumed at next iteration's park
      const u64* hp = (const u64*)(hbuf + ((size_t)(p * 8 + grp) * 16 + pb) * 256 + cj0);
      h0 = ALD64(hp + 0); h1 = ALD64(hp + 1); h2 = ALD64(hp + 2); h3 = ALD64(hp + 3);
    }
  }
}

extern "C" void kernel_launch(void* const* d_in, const int* in_sizes, int n_in,
                              void* d_out, int out_size, void* d_ws, size_t ws_size,
                              hipStream_t stream) {
  const float* x     = (const float*)d_in[0];
  const float* hx    = (const float*)d_in[1];
  const float* cx    = (const float*)d_in[2];
  const float* Wih_f = (const float*)d_in[3];
  const float* Whh_f = (const float*)d_in[4];
  const float* bih_f = (const float*)d_in[5];
  const float* bhh_f = (const float*)d_in[6];
  const float* Wih_r = (const float*)d_in[7];
  const float* Whh_r = (const float*)d_in[8];
  const float* bih_r = (const float*)d_in[9];
  const float* bhh_r = (const float*)d_in[10];
  float* out = (float*)d_out;

  u16* Wg      = (u16*)((char*)d_ws + WG_OFF);
  float* bias4 = (float*)((char*)d_ws + BIAS_OFF);
  u16* xb      = (u16*)((char*)d_ws + XB_OFF);
  u16* hbuf    = (u16*)((char*)d_ws + HB_OFF);
  u32* flags   = (u32*)((char*)d_ws + FL_OFF);

  // Request 86,016 B dynamic LDS (uses ~22 KB): forces 1 WG/CU.
  hipFuncSetAttribute((const void*)lstm_r13,
                      hipFuncAttributeMaxDynamicSharedMemorySize, 86016);

  hipLaunchKernelGGL(prep_kernel, dim3(2048), dim3(256), 0, stream,
                     x, Wih_f, Whh_f, bih_f, bhh_f, Wih_r, Whh_r, bih_r, bhh_r,
                     hx, Wg, bias4, xb, hbuf, flags);
  hipLaunchKernelGGL(lstm_r13, dim3(128), dim3(256), 86016, stream,
                     Wg, bias4, xb, cx, hbuf, flags, out);
}

// Round 14
// 2449.281 us; speedup vs baseline: 1.2923x; 1.2923x over previous
//
#include <hip/hip_runtime.h>
#include <cstddef>

#define T_STEPS 1024
#define NB      64
#define DIN     128
#define HID     256
#define WPG     8            // WGs per group

typedef unsigned short u16;
typedef unsigned int   u32;
typedef unsigned long long u64;
typedef __attribute__((ext_vector_type(8))) short short8;
typedef __attribute__((ext_vector_type(4))) float f32x4;

// ws byte offsets
#define WG_OFF   0u          // bf16 weights [2][1024 rows j*4+q][384 k] = 1,572,864 B
#define BIAS_OFF 1572864u    // f32 [2][1024]
#define XB_OFF   1581056u    // bf16 x [1024][64][128] = 16,777,216 B
#define HB_OFF   18358272u   // u16 hbuf [2 par][8 grp][16 b][256 j] = 131,072 B
#define FL_OFF   18489344u   // u32 flags [8 grp][8 wg] = 256 B

#define OUT_MAIN (T_STEPS * NB * 2 * HID)
#define TAIL_H   OUT_MAIN
#define TAIL_C   (OUT_MAIN + 2 * NB * HID)

__device__ __forceinline__ u16 f2bf(float f) {
  unsigned u = __float_as_uint(f);
  return (u16)((u + 0x7fffu + ((u >> 16) & 1u)) >> 16);  // RNE
}
__device__ __forceinline__ float sigm(float v) { return 1.f / (1.f + __expf(-v)); }
__device__ __forceinline__ float tanh_fast(float x) {
  float e = __expf(-2.f * fabsf(x));
  float r = (1.f - e) / (1.f + e);
  return x < 0.f ? -r : r;
}

__global__ void prep_kernel(const float* __restrict__ x,
                            const float* __restrict__ Wih_f, const float* __restrict__ Whh_f,
                            const float* __restrict__ bih_f, const float* __restrict__ bhh_f,
                            const float* __restrict__ Wih_r, const float* __restrict__ Whh_r,
                            const float* __restrict__ bih_r, const float* __restrict__ bhh_r,
                            const float* __restrict__ hx,
                            u16* __restrict__ Wg, float* __restrict__ bias4,
                            u16* __restrict__ xb, u16* __restrict__ hbuf,
                            u32* __restrict__ flags) {
  // segments: W 786432 | bias 2048 | xb 8388608 | hx-cells 32768 | flags 64
  const int total = 786432 + 2048 + 8388608 + 32768 + 64;
  for (int i = blockIdx.x * blockDim.x + threadIdx.x; i < total;
       i += gridDim.x * blockDim.x) {
    if (i < 786432) {
      int d = i / 393216;
      int r = i - d * 393216;
      int rowg = r / 384, k = r - rowg * 384;   // rowg = j*4+q interleaved
      int j = rowg >> 2, q = rowg & 3;
      int g = q * HID + j;                      // torch gate row
      const float* Wih = d ? Wih_r : Wih_f;
      const float* Whh = d ? Whh_r : Whh_f;
      float v = (k < DIN) ? Wih[g * DIN + k] : Whh[g * HID + (k - DIN)];
      Wg[i] = f2bf(v);
    } else if (i < 786432 + 2048) {
      int r = i - 786432;
      int d = r >> 10, rowg = r & 1023;
      int j = rowg >> 2, q = rowg & 3;
      int g = q * HID + j;
      bias4[r] = d ? (bih_r[g] + bhh_r[g]) : (bih_f[g] + bhh_f[g]);
    } else if (i < 786432 + 2048 + 8388608) {
      int r = i - (786432 + 2048);
      xb[r] = f2bf(x[r]);                       // [t][b][k]
    } else if (i < 786432 + 2048 + 8388608 + 32768) {
      int r = i - (786432 + 2048 + 8388608);    // (d*64+b)*256 + j
      int d = r >> 14, b = (r >> 8) & 63, j = r & 255;
      int grp = d * 4 + (b >> 4), bb = b & 15;
      hbuf[((size_t)(8 + grp) * 16 + bb) * 256 + j] = f2bf(hx[r]);  // parity 1
      hbuf[((size_t)(0 + grp) * 16 + bb) * 256 + j] = 0;            // parity 0
    } else {
      flags[i - (786432 + 2048 + 8388608 + 32768)] = 0u;
    }
  }
}

#define MFMA __builtin_amdgcn_mfma_f32_16x16x32_bf16
#define ALD64(P) __hip_atomic_load((P), __ATOMIC_RELAXED, __HIP_MEMORY_SCOPE_AGENT)
#define MN2(F) { u32 a_ = (u32)(F), b_ = (u32)((F) >> 32); \
                 mn = mn < a_ ? mn : a_; mn = mn < b_ ? mn : b_; }

// 64 WGs x 256 thr. grp = bid&7 = d*4+btile (8 WGs/group), jsl = bid>>3 (0..7).
// Per WG: 128 gate rows (2 n-tiles/wave), 16 batches. Weights in 24 named VGPR
// fragments (96 regs; r13 proved no spill at 12 -- launch_bounds(256,1) gives
// 512-reg budget). Exchange: r9 parity protocol, per-producer value flags
// (plain stores, no RMW), tid0-only poll, B1..B4 barriers.
__global__ __launch_bounds__(256, 1) void lstm_r14(
    const u16* __restrict__ Wg, const float* __restrict__ bias4,
    const u16* __restrict__ xb, const float* __restrict__ cx,
    u16* __restrict__ hbuf, u32* __restrict__ flags,
    float* __restrict__ out) {
  extern __shared__ char smem[];
  u16* xsh  = (u16*)smem;                 // [2][16][136]  8,704 B
  u16* hsh  = (u16*)(smem + 8704);        // [16][264]     8,448 B
  float* gl = (float*)(smem + 17152);     // [16 m][132 n] 8,448 B (tot 25,600)

  const int tid = threadIdx.x;
  const int bid = blockIdx.x;
  const int grp = bid & 7;
  const int jsl = bid >> 3;
  const int d = grp >> 2, b0 = (grp & 3) * 16;
  const int w = tid >> 6, l = tid & 63;

  // one-time: 24 weight fragments -> named VGPRs (16-B aligned global loads)
  // wave w owns gate rows [w*32, w*32+32) = 2 n-tiles within this WG's 128.
  const u16* wg0 = Wg + ((size_t)(d * 1024 + jsl * 128 + w * 32 + (l & 15))) * 384
                      + (l >> 4) * 8;
  const u16* wg1 = wg0 + 16 * 384;
#define LDW(P, O) (*(const short8*)((P) + (O)))
  short8 W0x0 = LDW(wg0, 0),   W0x1 = LDW(wg0, 32),  W0x2 = LDW(wg0, 64),  W0x3 = LDW(wg0, 96);
  short8 W0h0 = LDW(wg0, 128), W0h1 = LDW(wg0, 160), W0h2 = LDW(wg0, 192), W0h3 = LDW(wg0, 224);
  short8 W0h4 = LDW(wg0, 256), W0h5 = LDW(wg0, 288), W0h6 = LDW(wg0, 320), W0h7 = LDW(wg0, 352);
  short8 W1x0 = LDW(wg1, 0),   W1x1 = LDW(wg1, 32),  W1x2 = LDW(wg1, 64),  W1x3 = LDW(wg1, 96);
  short8 W1h0 = LDW(wg1, 128), W1h1 = LDW(wg1, 160), W1h2 = LDW(wg1, 192), W1h3 = LDW(wg1, 224);
  short8 W1h4 = LDW(wg1, 256), W1h5 = LDW(wg1, 288), W1h6 = LDW(wg1, 320), W1h7 = LDW(wg1, 352);
  const float bv0 = bias4[d * 1024 + jsl * 128 + w * 32 + (l & 15)];
  const float bv1 = bias4[d * 1024 + jsl * 128 + w * 32 + 16 + (l & 15)];

  // elementwise identity (r9 coalesced mapping): eb = batch, ej = j slot
  // thread handles local j = ej and ej+16 (2 cells)
  const int eb = tid >> 4, ej = tid & 15;
  const int jg0 = jsl * 32 + ej;            // global j of cell 0
  const int jg1 = jg0 + 16;                 // global j of cell 1
  float c0 = cx[((size_t)d * NB + b0 + eb) * HID + jg0];
  float c1 = cx[((size_t)d * NB + b0 + eb) * HID + jg1];

  const int xr_row = tid >> 4;            // x stage row (16 batches)
  const int xc = (tid & 15) * 8;          // 8 u16 = 16 B per thread
  const int pb = tid >> 4;                // h consumer batch
  const int cj0 = (tid & 15) * 16;        // 16 h cells per thread

  // prologue: stage x(t0), prefetch x(t1), issue h(init) loads (parity 1)
  { int t0 = d ? 1023 : 0;
    *(uint4*)&xsh[(0 * 16 + xr_row) * 136 + xc] =
        *(const uint4*)&xb[((size_t)t0 * NB + b0 + xr_row) * DIN + xc]; }
  uint4 xv;
  { int t1 = d ? 1022 : 1;
    xv = *(const uint4*)&xb[((size_t)t1 * NB + b0 + xr_row) * DIN + xc]; }
  u64 h0, h1, h2, h3;
  { const u64* hp = (const u64*)(hbuf + ((size_t)(8 + grp) * 16 + pb) * 256 + cj0);
    h0 = ALD64(hp + 0); h1 = ALD64(hp + 1); h2 = ALD64(hp + 2); h3 = ALD64(hp + 3); }
  __syncthreads();

  for (int s = 0; s < T_STEPS; ++s) {
    const int p = s & 1;
    const int t = d ? (1023 - s) : s;

    // park x(s+1) into the other buffer
    if (s < 1023) *(uint4*)&xsh[((p ^ 1) * 16 + xr_row) * 136 + xc] = xv;

    // x-part MFMA: A fragments shared by both n-tiles (hides in-flight h loads)
    f32x4 a0 = {bv0, bv0, bv0, bv0}, a1 = {bv1, bv1, bv1, bv1};
    {
      const u16* xr = &xsh[(p * 16 + (l & 15)) * 136 + (l >> 4) * 8];
      short8 X0 = *(const short8*)(xr + 0);
      short8 X1 = *(const short8*)(xr + 32);
      short8 X2 = *(const short8*)(xr + 64);
      short8 X3 = *(const short8*)(xr + 96);
      a0 = MFMA(X0, W0x0, a0, 0, 0, 0);  a1 = MFMA(X0, W1x0, a1, 0, 0, 0);
      a0 = MFMA(X1, W0x1, a0, 0, 0, 0);  a1 = MFMA(X1, W1x1, a1, 0, 0, 0);
      a0 = MFMA(X2, W0x2, a0, 0, 0, 0);  a1 = MFMA(X2, W1x2, a1, 0, 0, 0);
      a0 = MFMA(X3, W0x3, a0, 0, 0, 0);  a1 = MFMA(X3, W1x3, a1, 0, 0, 0);
    }
    // park h (waits vmcnt on h regs only)
    {
      uint4 H0, H1;
      H0.x = (u32)h0; H0.y = (u32)(h0 >> 32); H0.z = (u32)h1; H0.w = (u32)(h1 >> 32);
      H1.x = (u32)h2; H1.y = (u32)(h2 >> 32); H1.z = (u32)h3; H1.w = (u32)(h3 >> 32);
      *(uint4*)&hsh[pb * 264 + cj0] = H0;
      *(uint4*)&hsh[pb * 264 + cj0 + 8] = H1;
    }
    asm volatile("s_waitcnt lgkmcnt(0)" ::: "memory");
    __builtin_amdgcn_s_barrier();                // B1: h parked

    // h-part MFMA: A fragments shared across tiles, weights from VGPRs
    {
      const u16* hr = &hsh[(l & 15) * 264 + (l >> 4) * 8];
      short8 H;
      H = *(const short8*)(hr + 0);   a0 = MFMA(H, W0h0, a0, 0, 0, 0); a1 = MFMA(H, W1h0, a1, 0, 0, 0);
      H = *(const short8*)(hr + 32);  a0 = MFMA(H, W0h1, a0, 0, 0, 0); a1 = MFMA(H, W1h1, a1, 0, 0, 0);
      H = *(const short8*)(hr + 64);  a0 = MFMA(H, W0h2, a0, 0, 0, 0); a1 = MFMA(H, W1h2, a1, 0, 0, 0);
      H = *(const short8*)(hr + 96);  a0 = MFMA(H, W0h3, a0, 0, 0, 0); a1 = MFMA(H, W1h3, a1, 0, 0, 0);
      H = *(const short8*)(hr + 128); a0 = MFMA(H, W0h4, a0, 0, 0, 0); a1 = MFMA(H, W1h4, a1, 0, 0, 0);
      H = *(const short8*)(hr + 160); a0 = MFMA(H, W0h5, a0, 0, 0, 0); a1 = MFMA(H, W1h5, a1, 0, 0, 0);
      H = *(const short8*)(hr + 192); a0 = MFMA(H, W0h6, a0, 0, 0, 0); a1 = MFMA(H, W1h6, a1, 0, 0, 0);
      H = *(const short8*)(hr + 224); a0 = MFMA(H, W0h7, a0, 0, 0, 0); a1 = MFMA(H, W1h7, a1, 0, 0, 0);
    }
    // gates -> gl[m][n], n = local gate row (0..127)
    {
      int n0 = w * 32 + (l & 15);
      int m0 = (l >> 4) * 4;
      gl[(m0 + 0) * 132 + n0] = a0[0]; gl[(m0 + 1) * 132 + n0] = a0[1];
      gl[(m0 + 2) * 132 + n0] = a0[2]; gl[(m0 + 3) * 132 + n0] = a0[3];
      gl[(m0 + 0) * 132 + n0 + 16] = a1[0]; gl[(m0 + 1) * 132 + n0 + 16] = a1[1];
      gl[(m0 + 2) * 132 + n0 + 16] = a1[2]; gl[(m0 + 3) * 132 + n0 + 16] = a1[3];
    }
    asm volatile("s_waitcnt lgkmcnt(0)" ::: "memory");
    __builtin_amdgcn_s_barrier();                // B2: gates published

    // elementwise (2 cells/thread, r9-coalesced) + agent h-store
    float hA, hB, cA, cB;
    {
      f32x4 g4 = *(const f32x4*)&gl[eb * 132 + 4 * ej];
      float ii = sigm(g4[0]), ffg = sigm(g4[1]);
      float gg = tanh_fast(g4[2]), oo = sigm(g4[3]);
      cA = ffg * c0 + ii * gg; c0 = cA;
      hA = oo * tanh_fast(cA);
      f32x4 g5 = *(const f32x4*)&gl[eb * 132 + 64 + 4 * ej];
      float i2 = sigm(g5[0]), f2 = sigm(g5[1]);
      float g2 = tanh_fast(g5[2]), o2 = sigm(g5[3]);
      cB = f2 * c1 + i2 * g2; c1 = cB;
      hB = o2 * tanh_fast(cB);
      u16* hp = hbuf + ((size_t)(p * 8 + grp) * 16 + eb) * 256;
      __hip_atomic_store(hp + jg0, f2bf(hA), __ATOMIC_RELAXED, __HIP_MEMORY_SCOPE_AGENT);
      __hip_atomic_store(hp + jg1, f2bf(hB), __ATOMIC_RELAXED, __HIP_MEMORY_SCOPE_AGENT);
    }
    asm volatile("s_waitcnt vmcnt(0)" ::: "memory");   // h at LLC
    __builtin_amdgcn_s_barrier();                // B3: all h stores drained
    if (tid == 0 && s < 1023)
      __hip_atomic_store(flags + grp * 8 + jsl, (u32)(s + 1),
                         __ATOMIC_RELAXED, __HIP_MEMORY_SCOPE_AGENT);
    // fire-and-forget stores after the flag
    {
      float* op = out + ((size_t)t * NB + b0 + eb) * (2 * HID) + d * HID;
      op[jg0] = hA; op[jg1] = hB;
      if (s == 1023) {
        float* th = out + TAIL_H + ((size_t)d * NB + b0 + eb) * HID;
        float* tc = out + TAIL_C + ((size_t)d * NB + b0 + eb) * HID;
        th[jg0] = hA; th[jg1] = hB;
        tc[jg0] = cA; tc[jg1] = cB;
      }
    }
    // x prefetch for s+2
    if (s < 1022) {
      int tn = d ? (1021 - s) : (s + 2);
      xv = *(const uint4*)&xb[((size_t)tn * NB + b0 + xr_row) * DIN + xc];
    }
    if (s < 1023) {
      if (tid == 0) {
        const u64* fl = (const u64*)(flags + grp * 8);
        const u32 want = (u32)(s + 1);
        while (1) {
          u64 f0 = ALD64(fl + 0), f1 = ALD64(fl + 1);
          u64 f2 = ALD64(fl + 2), f3 = ALD64(fl + 3);
          u32 mn = 0xffffffffu;
          MN2(f0) MN2(f1) MN2(f2) MN2(f3)
          if (mn >= want) break;
          __builtin_amdgcn_s_sleep(1);
        }
      }
      __builtin_amdgcn_s_barrier();              // B4: group released
      // issue h(s) loads (parity p) -- consumed at next iteration's park
      const u64* hp = (const u64*)(hbuf + ((size_t)(p * 8 + grp) * 16 + pb) * 256 + cj0);
      h0 = ALD64(hp + 0); h1 = ALD64(hp + 1); h2 = ALD64(hp + 2); h3 = ALD64(hp + 3);
    }
  }
}

extern "C" void kernel_launch(void* const* d_in, const int* in_sizes, int n_in,
                              void* d_out, int out_size, void* d_ws, size_t ws_size,
                              hipStream_t stream) {
  const float* x     = (const float*)d_in[0];
  const float* hx    = (const float*)d_in[1];
  const float* cx    = (const float*)d_in[2];
  const float* Wih_f = (const float*)d_in[3];
  const float* Whh_f = (const float*)d_in[4];
  const float* bih_f = (const float*)d_in[5];
  const float* bhh_f = (const float*)d_in[6];
  const float* Wih_r = (const float*)d_in[7];
  const float* Whh_r = (const float*)d_in[8];
  const float* bih_r = (const float*)d_in[9];
  const float* bhh_r = (const float*)d_in[10];
  float* out = (float*)d_out;

  u16* Wg      = (u16*)((char*)d_ws + WG_OFF);
  float* bias4 = (float*)((char*)d_ws + BIAS_OFF);
  u16* xb      = (u16*)((char*)d_ws + XB_OFF);
  u16* hbuf    = (u16*)((char*)d_ws + HB_OFF);
  u32* flags   = (u32*)((char*)d_ws + FL_OFF);

  // Request 86,016 B dynamic LDS (uses ~25.6 KB): forces 1 WG/CU.
  hipFuncSetAttribute((const void*)lstm_r14,
                      hipFuncAttributeMaxDynamicSharedMemorySize, 86016);

  hipLaunchKernelGGL(prep_kernel, dim3(2048), dim3(256), 0, stream,
                     x, Wih_f, Whh_f, bih_f, bhh_f, Wih_r, Whh_r, bih_r, bhh_r,
                     hx, Wg, bias4, xb, hbuf, flags);
  hipLaunchKernelGGL(lstm_r14, dim3(64), dim3(256), 86016, stream,
                     Wg, bias4, xb, cx, hbuf, flags, out);
}